// Round 1
// baseline (446.354 us; speedup 1.0000x reference)
//
#include <hip/hip_runtime.h>
#include <math.h>

// CRF NLL: out[b] = logZ[b] - gold[b]
//   B=1024, L=512, T=64 (T == wavefront size -- lane j <-> tag j)
// One wave (64 threads) per batch element. E[i][j] = exp(trans[i][j]-cmax[j])
// held per-lane (column j) in 64 VGPRs; per step only 1 exp + 64 FMAs with
// p_i broadcast via ds_read_b128 from wave-private LDS.

#define TDIM 64

__global__ __launch_bounds__(64) void crf_fwd_kernel(
    const float* __restrict__ logits,  // [B, L, T]
    const int*   __restrict__ tags,    // [B, L]
    const int*   __restrict__ mask,    // [B, L]
    const float* __restrict__ trans,   // [T, T]
    float* __restrict__ out,           // [B]
    int B, int L)
{
    const int b = blockIdx.x;
    const int j = threadIdx.x;  // lane = tag index

    __shared__ __align__(16) float pbuf[2][TDIM];

    const float* lb = logits + (size_t)b * L * TDIM;
    const int*   tb = tags + (size_t)b * L;
    const int*   mb = mask + (size_t)b * L;

    // ---------------- gold path score ----------------
    float g = 0.f;
    for (int t = j; t < L; t += 64) {
        int   tag = tb[t];
        float mk  = (float)mb[t];
        float emit = lb[(size_t)t * TDIM + tag] * mk;
        float tr = 0.f;
        if (t > 0) {
            int ptag = tb[t - 1];
            tr = trans[ptag * TDIM + tag] * mk;
        }
        g += emit + tr;
    }
    #pragma unroll
    for (int o = 32; o >= 1; o >>= 1) g += __shfl_xor(g, o);
    // butterfly: every lane now holds gold[b]

    // ---------------- E column in registers ----------------
    float e[TDIM];
    #pragma unroll
    for (int i = 0; i < TDIM; ++i) e[i] = trans[i * TDIM + j];
    float cmax = -INFINITY;
    #pragma unroll
    for (int i = 0; i < TDIM; ++i) cmax = fmaxf(cmax, e[i]);
    #pragma unroll
    for (int i = 0; i < TDIM; ++i) e[i] = __expf(e[i] - cmax);

    // ---------------- forward recurrence ----------------
    float alpha = lb[j];                    // alpha0 = logits[b,0,:]
    float emit_next = lb[TDIM + j];         // prefetch t=1

    for (int t = 1; t < L; ++t) {
        float emit = emit_next;
        int tn = (t + 1 < L) ? (t + 1) : (L - 1);
        emit_next = lb[(size_t)tn * TDIM + j];   // prefetch (dead on last iter)
        int mk = mb[t];                          // uniform -> scalar load

        // wave max of alpha
        float m = alpha;
        #pragma unroll
        for (int o = 32; o >= 1; o >>= 1) m = fmaxf(m, __shfl_xor(m, o));

        float p = __expf(alpha - m);
        pbuf[t & 1][j] = p;
        __syncthreads();   // single-wave block: waitcnt + trivial barrier

        const float4* pv4 = (const float4*)pbuf[t & 1];
        float s0 = 0.f, s1 = 0.f, s2 = 0.f, s3 = 0.f;
        #pragma unroll
        for (int i = 0; i < TDIM; i += 4) {
            float4 pv = pv4[i >> 2];           // 16B LDS broadcast
            s0 = fmaf(pv.x, e[i + 0], s0);
            s1 = fmaf(pv.y, e[i + 1], s1);
            s2 = fmaf(pv.z, e[i + 2], s2);
            s3 = fmaf(pv.w, e[i + 3], s3);
        }
        float s = (s0 + s1) + (s2 + s3);

        float na = m + cmax + __logf(s) + emit;
        alpha = (mk > 0) ? na : alpha;
    }

    // ---------------- final logsumexp + output ----------------
    float m = alpha;
    #pragma unroll
    for (int o = 32; o >= 1; o >>= 1) m = fmaxf(m, __shfl_xor(m, o));
    float pz = __expf(alpha - m);
    #pragma unroll
    for (int o = 32; o >= 1; o >>= 1) pz += __shfl_xor(pz, o);
    float logZ = m + __logf(pz);

    if (j == 0) out[b] = logZ - g;
}

extern "C" void kernel_launch(void* const* d_in, const int* in_sizes, int n_in,
                              void* d_out, int out_size, void* d_ws, size_t ws_size,
                              hipStream_t stream) {
    const float* logits = (const float*)d_in[0];
    const int*   tags   = (const int*)d_in[1];
    const int*   mask   = (const int*)d_in[2];
    const float* trans  = (const float*)d_in[3];
    float* out = (float*)d_out;

    const int B = out_size;                 // 1024
    const int L = in_sizes[1] / B;          // 512
    // T fixed at 64 (== wavefront); trans is [64,64]

    crf_fwd_kernel<<<B, 64, 0, stream>>>(logits, tags, mask, trans, out, B, L);
}

// Round 2
// 364.189 us; speedup vs baseline: 1.2256x; 1.2256x over previous
//
#include <hip/hip_runtime.h>
#include <math.h>

// CRF NLL: out[b] = logZ[b] - gold[b].  B=1024, L=512, T=64 (lane j <-> tag j).
// One wave per batch element (1024 waves = 1/SIMD chip-wide -> latency-bound;
// everything below is about shortening the per-step serial chain).
//
// R2 changes vs R1 (318 us):
//  - no __syncthreads in the recurrence (it emitted s_waitcnt vmcnt(0) per step,
//    draining the emission prefetch). Single-wave DS ops are in-order; a
//    wave_barrier scheduling fence is enough for the ds_write -> ds_read.
//  - readfirstlane centering instead of 6-deep shfl-max chain (lse identity is
//    exact for any finite shift; spread across tags stays << fp32 range).
//  - 8-deep emission register pipeline (next 8-step block's loads issued one
//    block ahead), mask staged once into LDS with mask[0]:=0 so step 0 is a
//    uniform masked no-op.

#define TDIM 64
typedef float v2f __attribute__((ext_vector_type(2)));

__global__ __launch_bounds__(64) void crf_fwd_kernel(
    const float* __restrict__ logits,  // [B, L, T]
    const int*   __restrict__ tags,    // [B, L]
    const int*   __restrict__ mask,    // [B, L]
    const float* __restrict__ trans,   // [T, T]
    float* __restrict__ out,           // [B]
    int B, int L)
{
    const int b = blockIdx.x;
    const int j = threadIdx.x;  // lane = tag index

    __shared__ __align__(16) float pbuf[2][TDIM];
    __shared__ __align__(16) int   smask[512];

    const float* lb = logits + (size_t)b * L * TDIM;
    const int*   tb = tags + (size_t)b * L;
    const int*   mb = mask + (size_t)b * L;

    // ---- stage mask row into LDS (2 int4 per lane), override mask[0]=0 ----
    {
        const int4* m4 = (const int4*)mb;
        int4 a = m4[j * 2];
        int4 c = m4[j * 2 + 1];
        ((int4*)smask)[j * 2]     = a;
        ((int4*)smask)[j * 2 + 1] = c;
    }
    if (j == 0) smask[0] = 0;   // t=0 slot becomes a no-op update

    // ---------------- gold path score (one-time) ----------------
    float g = 0.f;
    for (int t = j; t < L; t += 64) {
        int   tag = tb[t];
        float mk  = (float)mb[t];
        float em  = lb[(size_t)t * TDIM + tag] * mk;
        float tr  = 0.f;
        if (t > 0) tr = trans[tb[t - 1] * TDIM + tag] * mk;
        g += em + tr;
    }
    #pragma unroll
    for (int o = 32; o >= 1; o >>= 1) g += __shfl_xor(g, o);

    // ---------------- E column in registers ----------------
    float e[TDIM];
    #pragma unroll
    for (int i = 0; i < TDIM; ++i) e[i] = trans[i * TDIM + j];
    float cmax = -INFINITY;
    #pragma unroll
    for (int i = 0; i < TDIM; ++i) cmax = fmaxf(cmax, e[i]);
    #pragma unroll
    for (int i = 0; i < TDIM; ++i) e[i] = __expf(e[i] - cmax);

    // ---------------- emission pipeline: block 0 (t = 0..7) ----------------
    float er[8];
    #pragma unroll
    for (int u = 0; u < 8; ++u) er[u] = lb[(size_t)u * TDIM + j];

    float alpha = er[0];                 // alpha0 = logits[b,0,:]

    int4 mc0 = ((const int4*)smask)[0];  // masks t=0..3 (t=0 forced 0)
    int4 mc1 = ((const int4*)smask)[1];  // masks t=4..7

    const int NB = L >> 3;               // 8-step blocks
    for (int k = 0; k < NB; ++k) {
        // -------- prefetch next block (emissions + masks) --------
        const int kn = (k + 1 < NB) ? (k + 1) : k;   // clamp (harmless reload)
        float en[8];
        #pragma unroll
        for (int u = 0; u < 8; ++u)
            en[u] = lb[(size_t)(kn * 8 + u) * TDIM + j];
        int4 mn0 = ((const int4*)smask)[kn * 2];
        int4 mn1 = ((const int4*)smask)[kn * 2 + 1];

        const int mks[8] = {mc0.x, mc0.y, mc0.z, mc0.w,
                            mc1.x, mc1.y, mc1.z, mc1.w};

        #pragma unroll
        for (int u = 0; u < 8; ++u) {
            // cheap uniform centering (exact lse identity for any shift)
            float m = __int_as_float(
                __builtin_amdgcn_readfirstlane(__float_as_int(alpha)));
            float p = __expf(alpha - m);

            const int par = u & 1;
            pbuf[par][j] = p;
            __builtin_amdgcn_wave_barrier();   // no reorder; DS is in-order per wave

            const float4* pv4 = (const float4*)pbuf[par];
            v2f a0 = {0.f, 0.f}, a1 = {0.f, 0.f};
            v2f a2 = {0.f, 0.f}, a3 = {0.f, 0.f};
            #pragma unroll
            for (int i = 0; i < 16; i += 2) {
                float4 f0 = pv4[i];            // uniform addr -> LDS broadcast
                float4 f1 = pv4[i + 1];
                v2f p0 = {f0.x, f0.y}, p1 = {f0.z, f0.w};
                v2f p2 = {f1.x, f1.y}, p3 = {f1.z, f1.w};
                v2f e0 = {e[4*i + 0], e[4*i + 1]};
                v2f e1 = {e[4*i + 2], e[4*i + 3]};
                v2f e2 = {e[4*i + 4], e[4*i + 5]};
                v2f e3 = {e[4*i + 6], e[4*i + 7]};
                a0 += p0 * e0;
                a1 += p1 * e1;
                a2 += p2 * e2;
                a3 += p3 * e3;
            }
            v2f av = (a0 + a1) + (a2 + a3);
            float s = av.x + av.y;

            float na = m + cmax + __logf(s) + er[u];
            alpha = (mks[u] > 0) ? na : alpha;
        }

        // -------- roll pipelines --------
        #pragma unroll
        for (int u = 0; u < 8; ++u) er[u] = en[u];
        mc0 = mn0; mc1 = mn1;
    }

    // ---------------- final exact logsumexp + output ----------------
    float m = alpha;
    #pragma unroll
    for (int o = 32; o >= 1; o >>= 1) m = fmaxf(m, __shfl_xor(m, o));
    float pz = __expf(alpha - m);
    #pragma unroll
    for (int o = 32; o >= 1; o >>= 1) pz += __shfl_xor(pz, o);
    float logZ = m + __logf(pz);

    if (j == 0) out[b] = logZ - g;
}

extern "C" void kernel_launch(void* const* d_in, const int* in_sizes, int n_in,
                              void* d_out, int out_size, void* d_ws, size_t ws_size,
                              hipStream_t stream) {
    const float* logits = (const float*)d_in[0];
    const int*   tags   = (const int*)d_in[1];
    const int*   mask   = (const int*)d_in[2];
    const float* trans  = (const float*)d_in[3];
    float* out = (float*)d_out;

    const int B = out_size;            // 1024
    const int L = in_sizes[1] / B;     // 512 (multiple of 8 assumed)

    crf_fwd_kernel<<<B, 64, 0, stream>>>(logits, tags, mask, trans, out, B, L);
}

// Round 3
// 357.280 us; speedup vs baseline: 1.2493x; 1.0193x over previous
//
#include <hip/hip_runtime.h>
#include <math.h>

// CRF NLL: out[b] = logZ[b] - gold[b].  B=1024, L=512, T=64 (lane j <-> tag j).
// One wave per batch element; strictly latency-bound (1 wave/SIMD chip-wide).
//
// R3: scaled-probability domain. q_j = exp(alpha_j - C). Per step:
//     q'_j = (sum_i q_i * E_ij) * X_j,  E = exp(trans) in VGPRs (one-time),
//     X = exp(emit) precomputed during the 8-deep prefetch (OFF the serial
//     chain). Renormalize by lane-0's power-of-2 exponent (bit ops + 1 mul,
//     no transcendental); kacc integer accumulates log2-scale. The critical
//     path per step is now: ds_write -> 16x ds_read_b128 -> 32 pk_fma tree ->
//     mul -> cndmask -> readfirstlane/bitops/mul. No exp, no log in the loop.

#define TDIM 64
typedef float v2f __attribute__((ext_vector_type(2)));

union F4 { float4 f; v2f h[2]; };

__global__ __launch_bounds__(64) void crf_fwd_kernel(
    const float* __restrict__ logits,  // [B, L, T]
    const int*   __restrict__ tags,    // [B, L]
    const int*   __restrict__ mask,    // [B, L]
    const float* __restrict__ trans,   // [T, T]
    float* __restrict__ out,           // [B]
    int B, int L)
{
    const int b = blockIdx.x;
    const int j = threadIdx.x;  // lane = tag index

    __shared__ __align__(16) float qbuf[TDIM];
    __shared__ __align__(16) int   smask[512];

    const float* lb = logits + (size_t)b * L * TDIM;
    const int*   tb = tags + (size_t)b * L;
    const int*   mb = mask + (size_t)b * L;

    // ---- stage mask row into LDS, override mask[0]=0 (t=0 is a no-op slot) --
    {
        const int4* m4 = (const int4*)mb;
        ((int4*)smask)[j * 2]     = m4[j * 2];
        ((int4*)smask)[j * 2 + 1] = m4[j * 2 + 1];
    }
    if (j == 0) smask[0] = 0;
    __builtin_amdgcn_wave_barrier();   // single wave: DS in-order suffices

    // ---------------- gold path score (one-time, off-chain) ----------------
    float g = 0.f;
    for (int t = j; t < L; t += 64) {
        int   tag = tb[t];
        float mk  = (float)mb[t];
        float em  = lb[(size_t)t * TDIM + tag] * mk;
        float tr  = 0.f;
        if (t > 0) tr = trans[tb[t - 1] * TDIM + tag] * mk;
        g += em + tr;
    }
    #pragma unroll
    for (int o = 32; o >= 1; o >>= 1) g += __shfl_xor(g, o);

    // ------------- E column (exp(trans[:,j])) packed into v2f regs ----------
    v2f epk[32];
    #pragma unroll
    for (int i = 0; i < 32; ++i) {
        float a = __expf(trans[(2 * i) * TDIM + j]);
        float c = __expf(trans[(2 * i + 1) * TDIM + j]);
        v2f t2 = {a, c};
        epk[i] = t2;
    }

    // ------------- emission pipeline: block 0, X = exp(emit) ----------------
    float e0[8];
    #pragma unroll
    for (int u = 0; u < 8; ++u) e0[u] = lb[(size_t)u * TDIM + j];
    float X[8];
    #pragma unroll
    for (int u = 0; u < 8; ++u) X[u] = __expf(e0[u]);

    // init: alpha0 = emit[0];  q = exp(alpha0 - base), base = lane0's alpha0
    float base = __int_as_float(
        __builtin_amdgcn_readfirstlane(__float_as_int(e0[0])));
    float q = __expf(e0[0] - base);
    int kacc = 0;

    int4 mc0 = ((const int4*)smask)[0];
    int4 mc1 = ((const int4*)smask)[1];

    const int NB = L >> 3;
    for (int k = 0; k < NB; ++k) {
        // ---- prefetch next block (emissions + masks), consumed at roll ----
        const int kn = (k + 1 < NB) ? (k + 1) : k;
        float en[8];
        #pragma unroll
        for (int u = 0; u < 8; ++u)
            en[u] = lb[(size_t)(kn * 8 + u) * TDIM + j];
        int4 mn0 = ((const int4*)smask)[kn * 2];
        int4 mn1 = ((const int4*)smask)[kn * 2 + 1];

        const int mks[8] = {mc0.x, mc0.y, mc0.z, mc0.w,
                            mc1.x, mc1.y, mc1.z, mc1.w};

        #pragma unroll
        for (int u = 0; u < 8; ++u) {
            // ---- serial chain ----
            qbuf[j] = q;
            __builtin_amdgcn_wave_barrier();

            const F4* pv4 = (const F4*)qbuf;
            v2f a0 = {0.f, 0.f}, a1 = {0.f, 0.f};
            v2f a2 = {0.f, 0.f}, a3 = {0.f, 0.f};
            #pragma unroll
            for (int i = 0; i < 16; ++i) {
                F4 f = pv4[i];                 // uniform addr -> LDS broadcast
                if (i & 1) {
                    a2 += f.h[0] * epk[2 * i];
                    a3 += f.h[1] * epk[2 * i + 1];
                } else {
                    a0 += f.h[0] * epk[2 * i];
                    a1 += f.h[1] * epk[2 * i + 1];
                }
            }
            v2f av = (a0 + a1) + (a2 + a3);
            float s = av.x + av.y;

            float q1 = s * X[u];
            q1 = (mks[u] > 0) ? q1 : q;

            // power-of-2 renorm to lane0 (no transcendental on the chain)
            int qb = __builtin_amdgcn_readfirstlane(__float_as_int(q1));
            int kk = (qb >> 23) - 127;          // exponent of q1 (q1 > 0)
            kacc += kk;
            float scale = __int_as_float((127 - kk) << 23);  // 2^-kk
            q = q1 * scale;
        }

        // ---- roll pipelines: exp of next emissions (off-chain) ----
        #pragma unroll
        for (int u = 0; u < 8; ++u) X[u] = __expf(en[u]);
        mc0 = mn0; mc1 = mn1;
    }

    // ---------------- final logsumexp + output ----------------
    float sum = q;
    #pragma unroll
    for (int o = 32; o >= 1; o >>= 1) sum += __shfl_xor(sum, o);
    float logZ = base + (float)kacc * 0.6931471805599453f + __logf(sum);

    if (j == 0) out[b] = logZ - g;
}

extern "C" void kernel_launch(void* const* d_in, const int* in_sizes, int n_in,
                              void* d_out, int out_size, void* d_ws, size_t ws_size,
                              hipStream_t stream) {
    const float* logits = (const float*)d_in[0];
    const int*   tags   = (const int*)d_in[1];
    const int*   mask   = (const int*)d_in[2];
    const float* trans  = (const float*)d_in[3];
    float* out = (float*)d_out;

    const int B = out_size;            // 1024
    const int L = in_sizes[1] / B;     // 512 (multiple of 8)

    crf_fwd_kernel<<<B, 64, 0, stream>>>(logits, tags, mask, trans, out, B, L);
}